// Round 1
// baseline (557.886 us; speedup 1.0000x reference)
//
#include <hip/hip_runtime.h>
#include <stdint.h>

#define S_LEN 2048
#define NH 16
#define HD 64
#define EMB 1024

typedef __attribute__((ext_vector_type(8))) short bf16x8;
typedef __attribute__((ext_vector_type(4))) float floatx4;

static __device__ __forceinline__ unsigned short f2bf(float f) {
  unsigned int u = __float_as_uint(f);
  unsigned int r = (u + 0x7FFFu + ((u >> 16) & 1u)) >> 16;
  return (unsigned short)r;
}

// ---------------- cast X f32 -> bf16 ----------------
__global__ void cast_x_kernel(const float* __restrict__ x, unsigned short* __restrict__ out, int n4) {
  int i = blockIdx.x * blockDim.x + threadIdx.x;
  if (i >= n4) return;
  float4 v = ((const float4*)x)[i];
  ushort4 o;
  o.x = f2bf(v.x); o.y = f2bf(v.y); o.z = f2bf(v.z); o.w = f2bf(v.w);
  ((ushort4*)out)[i] = o;
}

// ---------------- transpose+cast W[1024][1024] f32 -> WT[1024][1024] bf16 ----------------
__global__ void transpose_cast_kernel(const float* __restrict__ in, unsigned short* __restrict__ out) {
  __shared__ float tile[32][33];
  int x = blockIdx.x * 32 + threadIdx.x;
  int y0 = blockIdx.y * 32 + threadIdx.y;
#pragma unroll
  for (int j = 0; j < 4; j++)
    tile[threadIdx.y + 8 * j][threadIdx.x] = in[(y0 + 8 * j) * EMB + x];
  __syncthreads();
  int x2 = blockIdx.y * 32 + threadIdx.x;
  int y2 = blockIdx.x * 32 + threadIdx.y;
#pragma unroll
  for (int j = 0; j < 4; j++)
    out[(y2 + 8 * j) * EMB + x2] = f2bf(tile[threadIdx.x][threadIdx.y + 8 * j]);
}

// ---------------- bias LUT: lut[h][delta+2048] = rel_emb[bucket(delta)][h] ----------------
// T5 bucketing reduced to exact integer thresholds (matches float32 reference at the
// exactly-representable boundaries rp=16/32/64, inclusive side).
__global__ void build_lut_kernel(const float* __restrict__ rel_emb, float* __restrict__ lut) {
  int idx = blockIdx.x * blockDim.x + threadIdx.x; // 0..4095, delta = idx-2048
  if (idx >= 4096) return;
  int delta = idx - 2048;
  int bucket = (delta > 0) ? 16 : 0;
  int rp = (delta < 0) ? -delta : delta;
  int bl;
  if (rp < 8) bl = rp;
  else bl = 8 + (rp >= 12) + (rp >= 16) + (rp >= 23) + (rp >= 32) + (rp >= 46) + (rp >= 64) + (rp >= 91);
  bucket += bl;
#pragma unroll
  for (int h = 0; h < NH; h++)
    lut[h * 4096 + idx] = rel_emb[bucket * NH + h];
}

// ---------------- position_bias writer: [16,2048,2048] f32, memory-bound ----------------
__global__ void bias_out_kernel(const float* __restrict__ lut, float* __restrict__ dst) {
  int i = blockIdx.x * blockDim.x + threadIdx.x; // over 16*2048*512 float4s
  int h = i >> 20;
  int rem = i & 1048575;
  int q = rem >> 9;
  int k4 = (rem & 511) << 2;
  const float* lr = lut + h * 4096 + (k4 - q + 2048);
  float4 v = make_float4(__ldg(lr), __ldg(lr + 1), __ldg(lr + 2), __ldg(lr + 3));
  ((float4*)dst)[i] = v;
}

// ---------------- 128x128-tile bf16 MFMA GEMM: C[M,1024] = A[M,1024] @ BT^T ----------------
// MODE 0: write bf16 to [B,H,S,D] (Q/K) ; MODE 1: write bf16 to [B,H,D,S] (V) ; MODE 2: f32 [M,N]
template <int MODE>
__global__ __launch_bounds__(256) void gemm_kernel(const unsigned short* __restrict__ A,
                                                   const unsigned short* __restrict__ BT,
                                                   void* __restrict__ outp) {
  __shared__ __align__(16) unsigned short As[128 * 40];
  __shared__ __align__(16) unsigned short Bs[128 * 40];
  int tid = threadIdx.x;
  int mBase = blockIdx.y * 128;
  int nBase = blockIdx.x * 128;
  int wave = tid >> 6, lane = tid & 63;
  int wm = wave & 1, wn = wave >> 1;
  int quad = lane >> 4, lm = lane & 15;
  floatx4 acc[4][4];
#pragma unroll
  for (int i = 0; i < 4; i++)
#pragma unroll
    for (int j = 0; j < 4; j++) acc[i][j] = (floatx4){0.f, 0.f, 0.f, 0.f};

  for (int kt = 0; kt < 32; kt++) {
    int k0 = kt * 32;
#pragma unroll
    for (int cc = 0; cc < 2; cc++) {
      int c = tid + cc * 256;
      int row = c >> 2, kc = c & 3;
      *(uint4*)&As[row * 40 + kc * 8] = *(const uint4*)&A[(mBase + row) * 1024 + k0 + kc * 8];
      *(uint4*)&Bs[row * 40 + kc * 8] = *(const uint4*)&BT[(nBase + row) * 1024 + k0 + kc * 8];
    }
    __syncthreads();
    bf16x8 af[4], bfr[4];
#pragma unroll
    for (int i = 0; i < 4; i++) af[i] = *(const bf16x8*)&As[(wm * 64 + i * 16 + lm) * 40 + quad * 8];
#pragma unroll
    for (int j = 0; j < 4; j++) bfr[j] = *(const bf16x8*)&Bs[(wn * 64 + j * 16 + lm) * 40 + quad * 8];
#pragma unroll
    for (int i = 0; i < 4; i++)
#pragma unroll
      for (int j = 0; j < 4; j++)
        acc[i][j] = __builtin_amdgcn_mfma_f32_16x16x32_bf16(af[i], bfr[j], acc[i][j], 0, 0, 0);
    __syncthreads();
  }
#pragma unroll
  for (int i = 0; i < 4; i++) {
#pragma unroll
    for (int j = 0; j < 4; j++) {
#pragma unroll
      for (int r = 0; r < 4; r++) {
        int row = mBase + wm * 64 + i * 16 + quad * 4 + r;
        int col = nBase + wn * 64 + j * 16 + lm;
        float v = acc[i][j][r];
        if (MODE == 2) {
          ((float*)outp)[row * 1024 + col] = v;
        } else {
          int b = row >> 11, s = row & 2047;
          int h = col >> 6, d = col & 63;
          unsigned short* o = (unsigned short*)outp;
          if (MODE == 0) o[(((b * NH + h) * S_LEN + s) * HD) + d] = f2bf(v);
          else           o[(((b * NH + h) * HD + d) * S_LEN) + s] = f2bf(v);
        }
      }
    }
  }
}

// ---------------- flash attention with fused T5 bias ----------------
// grid (S/64, H, B), 4 waves; wave owns 16 q-rows; K-tiles of 64.
__global__ __launch_bounds__(256) void attn_kernel(const unsigned short* __restrict__ Qb,
                                                   const unsigned short* __restrict__ Kb,
                                                   const unsigned short* __restrict__ Vtb,
                                                   const float* __restrict__ lut,
                                                   unsigned short* __restrict__ Ob) {
  __shared__ __align__(16) unsigned short Kl[64 * 72];
  __shared__ __align__(16) unsigned short Vl[64 * 72];
  __shared__ __align__(16) unsigned short Pl[4 * 16 * 72];
  int tid = threadIdx.x;
  int wave = tid >> 6, lane = tid & 63;
  int quad = lane >> 4, lm = lane & 15;
  int h = blockIdx.y;
  int bh = blockIdx.z * NH + h;
  int qTile = blockIdx.x * 64;
  const unsigned short* Qp = Qb + (size_t)bh * S_LEN * HD;
  const unsigned short* Kp = Kb + (size_t)bh * S_LEN * HD;
  const unsigned short* Vp = Vtb + (size_t)bh * HD * S_LEN;
  const float* lrow = lut + h * 4096;

  int qr = qTile + wave * 16 + lm; // A-frag row (m = lane&15)
  bf16x8 aq0 = *(const bf16x8*)&Qp[qr * 64 + quad * 8];
  bf16x8 aq1 = *(const bf16x8*)&Qp[qr * 64 + 32 + quad * 8];

  float m_i[4], l_i[4];
  floatx4 accO[4];
#pragma unroll
  for (int r = 0; r < 4; r++) { m_i[r] = -1e30f; l_i[r] = 0.f; }
#pragma unroll
  for (int d = 0; d < 4; d++) accO[d] = (floatx4){0.f, 0.f, 0.f, 0.f};

  int q0 = qTile + wave * 16 + quad * 4; // C-layout row base

  for (int kt = 0; kt < 32; kt++) {
    int kBase = kt * 64;
    __syncthreads(); // previous tile's LDS reads complete before restage
#pragma unroll
    for (int cc = 0; cc < 2; cc++) {
      int c = tid + cc * 256;
      int row = c >> 3, sc = c & 7;
      *(uint4*)&Kl[row * 72 + sc * 8] = *(const uint4*)&Kp[(kBase + row) * 64 + sc * 8];
      *(uint4*)&Vl[row * 72 + sc * 8] = *(const uint4*)&Vp[row * 2048 + kBase + sc * 8];
    }
    __syncthreads();
    // S = Q K^T  (16 x 64 per wave)
    floatx4 s4[4];
#pragma unroll
    for (int nt = 0; nt < 4; nt++) {
      bf16x8 bk0 = *(const bf16x8*)&Kl[(nt * 16 + lm) * 72 + quad * 8];
      bf16x8 bk1 = *(const bf16x8*)&Kl[(nt * 16 + lm) * 72 + 32 + quad * 8];
      floatx4 z = (floatx4){0.f, 0.f, 0.f, 0.f};
      z = __builtin_amdgcn_mfma_f32_16x16x32_bf16(aq0, bk0, z, 0, 0, 0);
      z = __builtin_amdgcn_mfma_f32_16x16x32_bf16(aq1, bk1, z, 0, 0, 0);
      s4[nt] = z;
    }
    // + bias, row-max
    float mt[4] = {-1e30f, -1e30f, -1e30f, -1e30f};
#pragma unroll
    for (int nt = 0; nt < 4; nt++) {
      int kcol = kBase + nt * 16 + lm;
#pragma unroll
      for (int r = 0; r < 4; r++) {
        float sv = s4[nt][r] + __ldg(&lrow[kcol - (q0 + r) + 2048]);
        s4[nt][r] = sv;
        mt[r] = fmaxf(mt[r], sv);
      }
    }
#pragma unroll
    for (int off = 1; off < 16; off <<= 1)
#pragma unroll
      for (int r = 0; r < 4; r++) mt[r] = fmaxf(mt[r], __shfl_xor(mt[r], off, 64));
    float alpha[4], mn[4], rs[4];
#pragma unroll
    for (int r = 0; r < 4; r++) {
      mn[r] = fmaxf(m_i[r], mt[r]);
      alpha[r] = __expf(m_i[r] - mn[r]);
      m_i[r] = mn[r];
      rs[r] = 0.f;
    }
    float ps[4][4];
#pragma unroll
    for (int nt = 0; nt < 4; nt++)
#pragma unroll
      for (int r = 0; r < 4; r++) {
        float p = __expf(s4[nt][r] - mn[r]);
        ps[nt][r] = p;
        rs[r] += p;
      }
#pragma unroll
    for (int off = 1; off < 16; off <<= 1)
#pragma unroll
      for (int r = 0; r < 4; r++) rs[r] += __shfl_xor(rs[r], off, 64);
#pragma unroll
    for (int r = 0; r < 4; r++) l_i[r] = l_i[r] * alpha[r] + rs[r];
#pragma unroll
    for (int d = 0; d < 4; d++)
#pragma unroll
      for (int r = 0; r < 4; r++) accO[d][r] *= alpha[r];
    // P: C-layout -> A-layout via LDS (wave-private region)
    unsigned short* Pw = &Pl[wave * 16 * 72];
#pragma unroll
    for (int nt = 0; nt < 4; nt++)
#pragma unroll
      for (int r = 0; r < 4; r++)
        Pw[(quad * 4 + r) * 72 + nt * 16 + lm] = f2bf(ps[nt][r]);
    __syncthreads(); // order P writes before reads (uniform)
    bf16x8 pa0 = *(const bf16x8*)&Pw[lm * 72 + quad * 8];
    bf16x8 pa1 = *(const bf16x8*)&Pw[lm * 72 + 32 + quad * 8];
#pragma unroll
    for (int d = 0; d < 4; d++) {
      bf16x8 vb0 = *(const bf16x8*)&Vl[(d * 16 + lm) * 72 + quad * 8];
      bf16x8 vb1 = *(const bf16x8*)&Vl[(d * 16 + lm) * 72 + 32 + quad * 8];
      accO[d] = __builtin_amdgcn_mfma_f32_16x16x32_bf16(pa0, vb0, accO[d], 0, 0, 0);
      accO[d] = __builtin_amdgcn_mfma_f32_16x16x32_bf16(pa1, vb1, accO[d], 0, 0, 0);
    }
  }
  float inv[4];
#pragma unroll
  for (int r = 0; r < 4; r++) inv[r] = 1.f / l_i[r];
  int b = blockIdx.z;
#pragma unroll
  for (int d = 0; d < 4; d++)
#pragma unroll
    for (int r = 0; r < 4; r++) {
      int s = q0 + r;
      int gr = b * S_LEN + s;
      int col = h * 64 + d * 16 + lm;
      Ob[(size_t)gr * 1024 + col] = f2bf(accO[d][r] * inv[r]);
    }
}

extern "C" void kernel_launch(void* const* d_in, const int* in_sizes, int n_in,
                              void* d_out, int out_size, void* d_ws, size_t ws_size,
                              hipStream_t stream) {
  const float* X   = (const float*)d_in[0];
  const float* Wq  = (const float*)d_in[1];
  const float* Wk  = (const float*)d_in[2];
  const float* Wv  = (const float*)d_in[3];
  const float* Wo  = (const float*)d_in[4];
  const float* rel = (const float*)d_in[5];
  float* out = (float*)d_out;           // [2,2048,1024]
  float* bias_out = out + 4194304;      // [1,16,2048,2048]

  char* ws = (char*)d_ws;
  unsigned short* Xb  = (unsigned short*)(ws);
  unsigned short* WqT = (unsigned short*)(ws + (size_t)(8u  << 20));
  unsigned short* WkT = (unsigned short*)(ws + (size_t)(10u << 20));
  unsigned short* WvT = (unsigned short*)(ws + (size_t)(12u << 20));
  unsigned short* WoT = (unsigned short*)(ws + (size_t)(14u << 20));
  unsigned short* Qb  = (unsigned short*)(ws + (size_t)(16u << 20));
  unsigned short* Kb  = (unsigned short*)(ws + (size_t)(24u << 20));
  unsigned short* Vtb = (unsigned short*)(ws + (size_t)(32u << 20));
  unsigned short* Ob  = (unsigned short*)(ws + (size_t)(40u << 20));
  float* lut          = (float*)(ws + (size_t)(48u << 20));

  cast_x_kernel<<<4096, 256, 0, stream>>>(X, Xb, 1048576);
  dim3 tb(32, 8), tg(32, 32);
  transpose_cast_kernel<<<tg, tb, 0, stream>>>(Wq, WqT);
  transpose_cast_kernel<<<tg, tb, 0, stream>>>(Wk, WkT);
  transpose_cast_kernel<<<tg, tb, 0, stream>>>(Wv, WvT);
  transpose_cast_kernel<<<tg, tb, 0, stream>>>(Wo, WoT);
  build_lut_kernel<<<16, 256, 0, stream>>>(rel, lut);
  bias_out_kernel<<<65536, 256, 0, stream>>>(lut, bias_out);

  dim3 gg(8, 32); // N/128, M/128
  gemm_kernel<0><<<gg, 256, 0, stream>>>(Xb, WqT, (void*)Qb);
  gemm_kernel<0><<<gg, 256, 0, stream>>>(Xb, WkT, (void*)Kb);
  gemm_kernel<1><<<gg, 256, 0, stream>>>(Xb, WvT, (void*)Vtb);
  attn_kernel<<<dim3(32, 16, 2), 256, 0, stream>>>(Qb, Kb, Vtb, lut, Ob);
  gemm_kernel<2><<<gg, 256, 0, stream>>>(Ob, WoT, (void*)out);
}

// Round 3
// 478.851 us; speedup vs baseline: 1.1651x; 1.1651x over previous
//
#include <hip/hip_runtime.h>
#include <stdint.h>

#define S_LEN 2048
#define NH 16
#define EMB 1024

typedef __attribute__((ext_vector_type(8))) short bf16x8;
typedef __attribute__((ext_vector_type(4))) float floatx4;
typedef const __attribute__((address_space(1))) unsigned int* gas_u32p;
typedef __attribute__((address_space(3))) unsigned int* las_u32p;

static __device__ __forceinline__ void gld_lds16(const void* g, void* l) {
  __builtin_amdgcn_global_load_lds((gas_u32p)g, (las_u32p)l, 16, 0, 0);
}

static __device__ __forceinline__ unsigned short f2bf(float f) {
  unsigned int u = __float_as_uint(f);
  unsigned int r = (u + 0x7FFFu + ((u >> 16) & 1u)) >> 16;
  return (unsigned short)r;
}

// ---------------- cast X f32 -> bf16 ----------------
__global__ void cast_x_kernel(const float* __restrict__ x, unsigned short* __restrict__ out, int n4) {
  int i = blockIdx.x * blockDim.x + threadIdx.x;
  if (i >= n4) return;
  float4 v = ((const float4*)x)[i];
  ushort4 o;
  o.x = f2bf(v.x); o.y = f2bf(v.y); o.z = f2bf(v.z); o.w = f2bf(v.w);
  ((ushort4*)out)[i] = o;
}

// ---------------- transpose+cast up to 3 weights f32 -> WT bf16 ----------------
__global__ void transpose_cast3(const float* __restrict__ W0, const float* __restrict__ W1,
                                const float* __restrict__ W2, unsigned short* __restrict__ out) {
  __shared__ float tile[32][33];
  const float* in = (blockIdx.z == 0) ? W0 : ((blockIdx.z == 1) ? W1 : W2);
  unsigned short* o = out + (size_t)blockIdx.z * 1048576;
  int x = blockIdx.x * 32 + threadIdx.x;
  int y0 = blockIdx.y * 32 + threadIdx.y;
#pragma unroll
  for (int j = 0; j < 4; j++)
    tile[threadIdx.y + 8 * j][threadIdx.x] = in[(y0 + 8 * j) * EMB + x];
  __syncthreads();
  int x2 = blockIdx.y * 32 + threadIdx.x;
  int y2 = blockIdx.x * 32 + threadIdx.y;
#pragma unroll
  for (int j = 0; j < 4; j++)
    o[(y2 + 8 * j) * EMB + x2] = f2bf(tile[threadIdx.x][threadIdx.y + 8 * j]);
}

// ---------------- bias LUT: lut[h][delta+2048] ----------------
__global__ void build_lut_kernel(const float* __restrict__ rel_emb, float* __restrict__ lut) {
  int idx = blockIdx.x * blockDim.x + threadIdx.x;
  if (idx >= 4096) return;
  int delta = idx - 2048;
  int bucket = (delta > 0) ? 16 : 0;
  int rp = (delta < 0) ? -delta : delta;
  int bl;
  if (rp < 8) bl = rp;
  else bl = 8 + (rp >= 12) + (rp >= 16) + (rp >= 23) + (rp >= 32) + (rp >= 46) + (rp >= 64) + (rp >= 91);
  bucket += bl;
#pragma unroll
  for (int h = 0; h < NH; h++)
    lut[h * 4096 + idx] = rel_emb[bucket * NH + h];
}

// ---------------- position_bias writer: [16,2048,2048] f32 ----------------
__global__ void bias_out_kernel(const float* __restrict__ lut, float* __restrict__ dst) {
  int i = blockIdx.x * blockDim.x + threadIdx.x;
  int h = i >> 20;
  int rem = i & 1048575;
  int q = rem >> 9;
  int k4 = (rem & 511) << 2;
  const float* lr = lut + h * 4096 + (k4 - q + 2048);
  float4 v = make_float4(__ldg(lr), __ldg(lr + 1), __ldg(lr + 2), __ldg(lr + 3));
  ((float4*)dst)[i] = v;
}

// ---------------- m97-style 128x128 GEMM, global_load_lds + xor-swizzled LDS ----------------
// MODE 0: fused QKV epilogue (bf16 -> Qb/Kb [B,H,S,D], Vtb [B,H,D,S]); MODE 1: f32 [M,1024]
template <int MODE>
__global__ __launch_bounds__(256) void gemm2(const unsigned short* __restrict__ A,
                                             const unsigned short* __restrict__ BT,
                                             unsigned short* __restrict__ oQ,
                                             unsigned short* __restrict__ oK,
                                             unsigned short* __restrict__ oV,
                                             float* __restrict__ oF) {
  __shared__ __align__(16) unsigned short As[128 * 64];
  __shared__ __align__(16) unsigned short Bs[128 * 64];
  const int tid = threadIdx.x;
  const int wave = tid >> 6, lane = tid & 63;
  const int quad = lane >> 4, lm = lane & 15;
  const int wm = wave & 1, wn = wave >> 1;
  const int mBase = blockIdx.y * 128, nBase = blockIdx.x * 128;
  const int gg = (lane & 7) ^ (lane >> 3);  // granule swizzle, row&7 == lane>>3
  const int srow = lane >> 3;
  floatx4 acc[4][4];
#pragma unroll
  for (int i = 0; i < 4; i++)
#pragma unroll
    for (int j = 0; j < 4; j++) acc[i][j] = (floatx4){0.f, 0.f, 0.f, 0.f};

  for (int kt = 0; kt < 16; kt++) {
    int k0 = kt * 64;
    __syncthreads();
#pragma unroll
    for (int c = 0; c < 4; c++) {
      int chunk = wave * 4 + c;
      int row = chunk * 8 + srow;
      gld_lds16(&A[(size_t)(mBase + row) * 1024 + k0 + gg * 8], &As[chunk * 512]);
      gld_lds16(&BT[(size_t)(nBase + row) * 1024 + k0 + gg * 8], &Bs[chunk * 512]);
    }
    __syncthreads();
#pragma unroll
    for (int hh = 0; hh < 2; hh++) {
      bf16x8 af[4], bfr[4];
#pragma unroll
      for (int i = 0; i < 4; i++)
        af[i] = *(const bf16x8*)&As[(wm * 64 + i * 16 + lm) * 64 + (((hh << 2) + quad) ^ (lm & 7)) * 8];
#pragma unroll
      for (int j = 0; j < 4; j++)
        bfr[j] = *(const bf16x8*)&Bs[(wn * 64 + j * 16 + lm) * 64 + (((hh << 2) + quad) ^ (lm & 7)) * 8];
#pragma unroll
      for (int i = 0; i < 4; i++)
#pragma unroll
        for (int j = 0; j < 4; j++)
          acc[i][j] = __builtin_amdgcn_mfma_f32_16x16x32_bf16(af[i], bfr[j], acc[i][j], 0, 0, 0);
    }
  }
  const int which = nBase >> 10;  // uniform per block (128 | 1024)
#pragma unroll
  for (int i = 0; i < 4; i++) {
#pragma unroll
    for (int j = 0; j < 4; j++) {
#pragma unroll
      for (int r = 0; r < 4; r++) {
        int row = mBase + wm * 64 + i * 16 + quad * 4 + r;
        int col = nBase + wn * 64 + j * 16 + lm;
        float v = acc[i][j][r];
        if (MODE == 1) {
          oF[(size_t)row * 1024 + col] = v;
        } else {
          int b = row >> 11, s = row & 2047;
          int cw = col & 1023;
          int h = cw >> 6, d = cw & 63;
          if (which == 0)      oQ[(((size_t)(b * NH + h) * S_LEN + s) * 64) + d] = f2bf(v);
          else if (which == 1) oK[(((size_t)(b * NH + h) * S_LEN + s) * 64) + d] = f2bf(v);
          else                 oV[(((size_t)(b * NH + h) * 64 + d) * S_LEN) + s] = f2bf(v);
        }
      }
    }
  }
}

// ---------------- flash attention, single-pass softmax (no online max) ----------------
// grid (S/128, H, B), 4 waves; wave owns 32 q-rows (2 groups of 16). K-tiles of 64.
// Scores via K·Q^T so P exits MFMA with 4 consecutive k per thread -> b64 P writes.
__global__ __launch_bounds__(256) void attn_kernel(const unsigned short* __restrict__ Qb,
                                                   const unsigned short* __restrict__ Kb,
                                                   const unsigned short* __restrict__ Vtb,
                                                   const float* __restrict__ lut,
                                                   unsigned short* __restrict__ Ob) {
  __shared__ __align__(16) unsigned short Kl[64 * 64];
  __shared__ __align__(16) unsigned short Vl[64 * 64];
  __shared__ __align__(16) unsigned short Pl[4 * 16 * 72];
  const int tid = threadIdx.x;
  const int wave = tid >> 6, lane = tid & 63;
  const int quad = lane >> 4, lm = lane & 15;
  const int h = blockIdx.y, b = blockIdx.z;
  const int bh = b * NH + h;
  const int qTile = blockIdx.x * 128;
  const unsigned short* Qp = Qb + (size_t)bh * S_LEN * 64;
  const unsigned short* Kp = Kb + (size_t)bh * S_LEN * 64;
  const unsigned short* Vp = Vtb + (size_t)bh * 64 * S_LEN;
  const float* lrow = lut + h * 4096;
  const float cneg = lrow[0], cpos = lrow[4095];
  const int gg = (lane & 7) ^ (lane >> 3);
  const int srow = lane >> 3;
  const int qw = qTile + wave * 32;

  bf16x8 aq[2][2];
#pragma unroll
  for (int g = 0; g < 2; g++)
#pragma unroll
    for (int hh = 0; hh < 2; hh++)
      aq[g][hh] = *(const bf16x8*)&Qp[(qw + g * 16 + lm) * 64 + hh * 32 + quad * 8];

  floatx4 accO[2][4];
#pragma unroll
  for (int g = 0; g < 2; g++)
#pragma unroll
    for (int d = 0; d < 4; d++) accO[g][d] = (floatx4){0.f, 0.f, 0.f, 0.f};
  float lp[2] = {0.f, 0.f};  // partial row-sum for q = qw + g*16 + lm

  unsigned short* Pw = &Pl[wave * 16 * 72];

  for (int kt = 0; kt < 32; kt++) {
    int kBase = kt * 64;
    __syncthreads();
#pragma unroll
    for (int c = 0; c < 2; c++) {
      int chunk = wave * 2 + c;
      int row = chunk * 8 + srow;
      gld_lds16(&Kp[(size_t)(kBase + row) * 64 + gg * 8], &Kl[chunk * 512]);
      gld_lds16(&Vp[(size_t)row * S_LEN + kBase + gg * 8], &Vl[chunk * 512]);
    }
    __syncthreads();

    bf16x8 kf[4][2], vf[4][2];
#pragma unroll
    for (int nt = 0; nt < 4; nt++)
#pragma unroll
      for (int hh = 0; hh < 2; hh++) {
        int off = (nt * 16 + lm) * 64 + (((hh << 2) + quad) ^ (lm & 7)) * 8;
        kf[nt][hh] = *(const bf16x8*)&Kl[off];
        vf[nt][hh] = *(const bf16x8*)&Vl[off];
      }

    bool farTile = (kBase + 154 <= qTile) || (kBase >= qTile + 218);
    float cfar = (kBase < qTile) ? cneg : cpos;

#pragma unroll
    for (int g = 0; g < 2; g++) {
      int q = qw + g * 16 + lm;
      // S^T tile: Z[k_local][q_local] = K·Q^T ; thread holds q=lm, k=nt*16+quad*4+r
      floatx4 s4[4];
#pragma unroll
      for (int nt = 0; nt < 4; nt++) {
        floatx4 z = (floatx4){0.f, 0.f, 0.f, 0.f};
        z = __builtin_amdgcn_mfma_f32_16x16x32_bf16(kf[nt][0], aq[g][0], z, 0, 0, 0);
        z = __builtin_amdgcn_mfma_f32_16x16x32_bf16(kf[nt][1], aq[g][1], z, 0, 0, 0);
        s4[nt] = z;
      }
      float psum = 0.f;
#pragma unroll
      for (int nt = 0; nt < 4; nt++) {
        union { unsigned short u[4]; uint2 v; } pk;
#pragma unroll
        for (int r = 0; r < 4; r++) {
          float sv;
          if (farTile) sv = s4[nt][r] + cfar;
          else {
            int kcol = kBase + nt * 16 + quad * 4 + r;
            sv = s4[nt][r] + __ldg(&lrow[kcol - q + 2048]);
          }
          float p = __expf(sv);
          psum += p;
          pk.u[r] = f2bf(p);
        }
        *(uint2*)&Pw[lm * 72 + nt * 16 + quad * 4] = pk.v;  // P[q=lm][k..k+3]
      }
      lp[g] += psum;
      // P as A-frag (same-wave DS ordering makes this safe without a barrier)
      bf16x8 pa0 = *(const bf16x8*)&Pw[lm * 72 + quad * 8];
      bf16x8 pa1 = *(const bf16x8*)&Pw[lm * 72 + 32 + quad * 8];
#pragma unroll
      for (int d = 0; d < 4; d++) {
        accO[g][d] = __builtin_amdgcn_mfma_f32_16x16x32_bf16(pa0, vf[d][0], accO[g][d], 0, 0, 0);
        accO[g][d] = __builtin_amdgcn_mfma_f32_16x16x32_bf16(pa1, vf[d][1], accO[g][d], 0, 0, 0);
      }
    }
  }
  // finalize: reduce row-sums across quads, redistribute, normalize, store
#pragma unroll
  for (int g = 0; g < 2; g++) {
    lp[g] += __shfl_xor(lp[g], 16, 64);
    lp[g] += __shfl_xor(lp[g], 32, 64);
  }
#pragma unroll
  for (int g = 0; g < 2; g++) {
    float linv[4];
#pragma unroll
    for (int r = 0; r < 4; r++) linv[r] = 1.f / __shfl(lp[g], quad * 4 + r, 64);
#pragma unroll
    for (int d = 0; d < 4; d++)
#pragma unroll
      for (int r = 0; r < 4; r++) {
        int q = qw + g * 16 + quad * 4 + r;
        int col = h * 64 + d * 16 + lm;
        Ob[((size_t)(b * S_LEN + q)) * 1024 + col] = f2bf(accO[g][d][r] * linv[r]);
      }
  }
}

extern "C" void kernel_launch(void* const* d_in, const int* in_sizes, int n_in,
                              void* d_out, int out_size, void* d_ws, size_t ws_size,
                              hipStream_t stream) {
  const float* X   = (const float*)d_in[0];
  const float* Wq  = (const float*)d_in[1];
  const float* Wk  = (const float*)d_in[2];
  const float* Wv  = (const float*)d_in[3];
  const float* Wo  = (const float*)d_in[4];
  const float* rel = (const float*)d_in[5];
  float* out = (float*)d_out;           // [2,2048,1024]
  float* bias_out = out + 4194304;      // [1,16,2048,2048]

  char* ws = (char*)d_ws;
  unsigned short* Xb    = (unsigned short*)(ws);
  unsigned short* WqkvT = (unsigned short*)(ws + (size_t)(8u  << 20));  // 3 x 2MB
  unsigned short* WoT   = (unsigned short*)(ws + (size_t)(14u << 20));
  unsigned short* Qb    = (unsigned short*)(ws + (size_t)(16u << 20));
  unsigned short* Kb    = (unsigned short*)(ws + (size_t)(24u << 20));
  unsigned short* Vtb   = (unsigned short*)(ws + (size_t)(32u << 20));
  unsigned short* Ob    = (unsigned short*)(ws + (size_t)(40u << 20));
  float* lut            = (float*)(ws + (size_t)(48u << 20));

  cast_x_kernel<<<4096, 256, 0, stream>>>(X, Xb, 1048576);
  dim3 tb(32, 8);
  transpose_cast3<<<dim3(32, 32, 3), tb, 0, stream>>>(Wq, Wk, Wv, WqkvT);
  transpose_cast3<<<dim3(32, 32, 1), tb, 0, stream>>>(Wo, Wo, Wo, WoT);
  build_lut_kernel<<<16, 256, 0, stream>>>(rel, lut);
  bias_out_kernel<<<65536, 256, 0, stream>>>(lut, bias_out);

  gemm2<0><<<dim3(24, 32), 256, 0, stream>>>(Xb, WqkvT, Qb, Kb, Vtb, nullptr);
  attn_kernel<<<dim3(16, 16, 2), 256, 0, stream>>>(Qb, Kb, Vtb, lut, Ob);
  gemm2<1><<<dim3(8, 32), 256, 0, stream>>>(Ob, WoT, nullptr, nullptr, nullptr, out);
}